// Round 9
// baseline (255.694 us; speedup 1.0000x reference)
//
#include <hip/hip_runtime.h>

// BCE loss reduction over (64,8,65536,1) fp32 pred/true.
// loss = -sum(t*max(log p,-100) + (1-t)*max(log(1-p),-100)) / (65536*64)
// log2-domain: bce_elem = lq + t*(lp-lq); scale by -ln2/4194304 at the end.
//
// Ladder so far: R1-R6 all structures ~103-108 us (~2.6 TB/s) regardless of
// MLP depth / LDS-DMA / occupancy => L1 allocation path was the binder for
// zero-reuse streams. R8: nt loads (L1 bypass) -> kernel ~79 us (~3.4 TB/s).
// R9: nt + R3's double-buffered software pipeline (8 loads in flight at
// issue, sched_barrier fences) — test whether per-wave MLP binds now that
// the L1 path is out and effective latency is longer.

#define LOG2_CLAMP -144.26950408889634f   // -100 / ln(2)

typedef float vfloat4 __attribute__((ext_vector_type(4)));

__device__ __forceinline__ vfloat4 ntload(const vfloat4* a) {
    return __builtin_nontemporal_load(a);
}

__device__ __forceinline__ void bce4_acc(vfloat4 p, vfloat4 t,
                                         float& sq, float& sd) {
    float lp, lq;
    lp = fmaxf(__log2f(p.x), LOG2_CLAMP);
    lq = fmaxf(__log2f(1.0f - p.x), LOG2_CLAMP);   // 1-p exact for p>=0.5
    sq += lq; sd = __builtin_fmaf(t.x, lp - lq, sd);
    lp = fmaxf(__log2f(p.y), LOG2_CLAMP);
    lq = fmaxf(__log2f(1.0f - p.y), LOG2_CLAMP);
    sq += lq; sd = __builtin_fmaf(t.y, lp - lq, sd);
    lp = fmaxf(__log2f(p.z), LOG2_CLAMP);
    lq = fmaxf(__log2f(1.0f - p.z), LOG2_CLAMP);
    sq += lq; sd = __builtin_fmaf(t.z, lp - lq, sd);
    lp = fmaxf(__log2f(p.w), LOG2_CLAMP);
    lq = fmaxf(__log2f(1.0f - p.w), LOG2_CLAMP);
    sq += lq; sd = __builtin_fmaf(t.w, lp - lq, sd);
}

__global__ __launch_bounds__(256) void vertical_loss_kernel(
    const vfloat4* __restrict__ p4,
    const vfloat4* __restrict__ t4,
    float* __restrict__ out,
    int n4, float final_scale)
{
    float sq = 0.0f, sd = 0.0f;

    const int chunk = n4 / (int)gridDim.x;           // float4s per block
    const int steps = chunk / (int)blockDim.x;       // iterations per thread

    if ((chunk % (int)blockDim.x) == 0 && (steps & 3) == 0 && steps >= 8) {
        // Block-contiguous tiles, 4x-unrolled, software-pipelined, nt loads.
        const int stp = (int)blockDim.x;             // 256
        int i = (int)blockIdx.x * chunk + (int)threadIdx.x;

        vfloat4 P0 = ntload(&p4[i]);
        vfloat4 P1 = ntload(&p4[i + stp]);
        vfloat4 P2 = ntload(&p4[i + 2 * stp]);
        vfloat4 P3 = ntload(&p4[i + 3 * stp]);
        vfloat4 T0 = ntload(&t4[i]);
        vfloat4 T1 = ntload(&t4[i + stp]);
        vfloat4 T2 = ntload(&t4[i + 2 * stp]);
        vfloat4 T3 = ntload(&t4[i + 3 * stp]);

        const int groups = steps >> 2;               // 4 for bench shape
        for (int g = 1; g < groups; ++g) {
            i += 4 * stp;
            // Fence: next group's loads may not sink below, compute may not
            // hoist above (machine-scheduler barrier).
            __builtin_amdgcn_sched_barrier(0);
            vfloat4 Q0 = ntload(&p4[i]);
            vfloat4 Q1 = ntload(&p4[i + stp]);
            vfloat4 Q2 = ntload(&p4[i + 2 * stp]);
            vfloat4 Q3 = ntload(&p4[i + 3 * stp]);
            vfloat4 U0 = ntload(&t4[i]);
            vfloat4 U1 = ntload(&t4[i + stp]);
            vfloat4 U2 = ntload(&t4[i + 2 * stp]);
            vfloat4 U3 = ntload(&t4[i + 3 * stp]);
            __builtin_amdgcn_sched_barrier(0);
            bce4_acc(P0, T0, sq, sd);
            bce4_acc(P1, T1, sq, sd);
            bce4_acc(P2, T2, sq, sd);
            bce4_acc(P3, T3, sq, sd);
            P0 = Q0; P1 = Q1; P2 = Q2; P3 = Q3;
            T0 = U0; T1 = U1; T2 = U2; T3 = U3;
        }
        bce4_acc(P0, T0, sq, sd);
        bce4_acc(P1, T1, sq, sd);
        bce4_acc(P2, T2, sq, sd);
        bce4_acc(P3, T3, sq, sd);
    } else {
        // Generic fallback (not taken for the bench shape).
        for (int i = (int)blockIdx.x * (int)blockDim.x + (int)threadIdx.x;
             i < n4; i += (int)gridDim.x * (int)blockDim.x) {
            vfloat4 p = ntload(&p4[i]);
            vfloat4 t = ntload(&t4[i]);
            bce4_acc(p, t, sq, sd);
        }
    }

    float sum = sq + sd;

    // wave (64-lane) reduction
    #pragma unroll
    for (int off = 32; off > 0; off >>= 1)
        sum += __shfl_down(sum, off, 64);

    __shared__ float wsum[4];  // 256 threads = 4 waves
    int wave = threadIdx.x >> 6;
    int lane = threadIdx.x & 63;
    if (lane == 0) wsum[wave] = sum;
    __syncthreads();

    if (threadIdx.x == 0) {
        float s = wsum[0] + wsum[1] + wsum[2] + wsum[3];
        atomicAdd(out, s * final_scale);  // device-scope by default on CDNA
    }
}

extern "C" void kernel_launch(void* const* d_in, const int* in_sizes, int n_in,
                              void* d_out, int out_size, void* d_ws, size_t ws_size,
                              hipStream_t stream) {
    const vfloat4* pred  = (const vfloat4*)d_in[0];
    const vfloat4* true_ = (const vfloat4*)d_in[1];
    float* out = (float*)d_out;

    int n  = in_sizes[0];   // 33,554,432
    int n4 = n / 4;         // 8,388,608 float4s
    // loss = -ln2 * (sq+sd)_total / (65536*64)
    float final_scale = -0.69314718055994531f / (65536.0f * 64.0f);

    // Harness re-poisons d_out with 0xAA before every launch — zero it.
    (void)hipMemsetAsync(d_out, 0, sizeof(float), stream);

    // 2048 blocks x 256 threads: contiguous 4096-float4 chunk per block,
    // 16 iterations/thread = 4 pipelined groups of 4; 32 waves/CU.
    int blocks = 2048;
    vertical_loss_kernel<<<blocks, 256, 0, stream>>>(pred, true_, out, n4, final_scale);
}